// Round 1
// baseline (10390.288 us; speedup 1.0000x reference)
//
#include <hip/hip_runtime.h>
#include <stdint.h>
#include <math.h>

#define Bn 32768
#define Ln 7
#define Tn 6
#define En 256
#define Hn 256
#define Rr 16
#define NEGF (-1000000000.0f)

// ---------------------------------------------------------------------------
// ws layout (floats):
//   [0, 7*65536)            : 7 transposed weight matrices WT[m][e][h]
//                             order: Wh, Wv, Wsh, Wsv, Wedge, Win, Wctx
//   [458752, 458752+B*7)    : att[b][l]
//   [688128, 688142)        : S[7], logS[7]
// ---------------------------------------------------------------------------

__device__ __forceinline__ uint32_t rotl32(uint32_t x, int d) {
  return (x << d) | (x >> (32 - d));
}

// JAX threefry2x32, 20 rounds (matches jax/_src/prng.py)
__device__ __forceinline__ void threefry2x32(uint32_t k0, uint32_t k1,
                                             uint32_t x0, uint32_t x1,
                                             uint32_t& o0, uint32_t& o1) {
  uint32_t k2 = k0 ^ k1 ^ 0x1BD11BDAu;
  x0 += k0; x1 += k1;
  // group A rotations {13,15,26,6}
  x0 += x1; x1 = rotl32(x1, 13); x1 ^= x0;
  x0 += x1; x1 = rotl32(x1, 15); x1 ^= x0;
  x0 += x1; x1 = rotl32(x1, 26); x1 ^= x0;
  x0 += x1; x1 = rotl32(x1,  6); x1 ^= x0;
  x0 += k1; x1 += k2 + 1u;
  // group B rotations {17,29,16,24}
  x0 += x1; x1 = rotl32(x1, 17); x1 ^= x0;
  x0 += x1; x1 = rotl32(x1, 29); x1 ^= x0;
  x0 += x1; x1 = rotl32(x1, 16); x1 ^= x0;
  x0 += x1; x1 = rotl32(x1, 24); x1 ^= x0;
  x0 += k2; x1 += k0 + 2u;
  x0 += x1; x1 = rotl32(x1, 13); x1 ^= x0;
  x0 += x1; x1 = rotl32(x1, 15); x1 ^= x0;
  x0 += x1; x1 = rotl32(x1, 26); x1 ^= x0;
  x0 += x1; x1 = rotl32(x1,  6); x1 ^= x0;
  x0 += k0; x1 += k1 + 3u;
  x0 += x1; x1 = rotl32(x1, 17); x1 ^= x0;
  x0 += x1; x1 = rotl32(x1, 29); x1 ^= x0;
  x0 += x1; x1 = rotl32(x1, 16); x1 ^= x0;
  x0 += x1; x1 = rotl32(x1, 24); x1 ^= x0;
  x0 += k1; x1 += k2 + 4u;
  x0 += x1; x1 = rotl32(x1, 13); x1 ^= x0;
  x0 += x1; x1 = rotl32(x1, 15); x1 ^= x0;
  x0 += x1; x1 = rotl32(x1, 26); x1 ^= x0;
  x0 += x1; x1 = rotl32(x1,  6); x1 ^= x0;
  x0 += k2; x1 += k0 + 5u;
  o0 = x0; o1 = x1;
}

// ---------------------------------------------------------------------------
// Transpose the 7 weight matrices (256x256 each) into ws.
// ---------------------------------------------------------------------------
__global__ __launch_bounds__(256) void k_transpose(
    const float* __restrict__ w0, const float* __restrict__ w1,
    const float* __restrict__ w2, const float* __restrict__ w3,
    const float* __restrict__ w4, const float* __restrict__ w5,
    const float* __restrict__ w6, float* __restrict__ dst) {
  const float* src;
  switch (blockIdx.y) {
    case 0: src = w0; break;
    case 1: src = w1; break;
    case 2: src = w2; break;
    case 3: src = w3; break;
    case 4: src = w4; break;
    case 5: src = w5; break;
    default: src = w6; break;
  }
  int e = blockIdx.x;       // grid.x = 256
  int h = threadIdx.x;      // 256 threads
  dst[(size_t)blockIdx.y * 65536 + e * 256 + h] = src[h * 256 + e];
}

// ---------------------------------------------------------------------------
// Main fused kernel: one WG (256 threads, thread = h channel) per 16 rows.
// Produces att[b][l] (post-mask, post 10*tanh).
// ---------------------------------------------------------------------------
__global__ __launch_bounds__(256, 2) void k_main(
    const float* __restrict__ enc, const int* __restrict__ xes,
    const int* __restrict__ maskp, const float* __restrict__ wt,
    const float* __restrict__ b_in, const float* __restrict__ b_ctx,
    const float* __restrict__ V, float* __restrict__ att_out) {
  const int t = threadIdx.x;
  const int b0 = blockIdx.x * Rr;

  const float* WhT   = wt;
  const float* WvT   = wt + 65536;
  const float* WshT  = wt + 2 * 65536;
  const float* WsvT  = wt + 3 * 65536;
  const float* WeT   = wt + 4 * 65536;
  const float* WinT  = wt + 5 * 65536;
  const float* WctxT = wt + 6 * 65536;

  __shared__ int s_offh[5][Rr];
  __shared__ int s_offv[5][Rr];
  __shared__ int s_cond[5][Rr];
  __shared__ float xbuf[256 * 20];   // broadcast buffer [e][20] (16 rows + pad)
  __shared__ float red[4][Rr];

  if (t < 5 * Rr) {
    int tt = t >> 4, r = t & 15;
    int base = ((b0 + r) * Tn + tt) * 3;
    int hi = xes[base], vi = xes[base + 1], tc = xes[base + 2];
    s_offh[tt][r] = ((b0 + r) * Ln + hi) * En;
    s_offv[tt][r] = ((b0 + r) * Ln + vi) * En;
    s_cond[tt][r] = (tc == 0) ? 1 : 0;
  }
  __syncthreads();

  // ---- stage 1: edges for t=0..4, acc[tt][r] in registers --------------
  float acc[5][Rr];
#pragma unroll
  for (int i = 0; i < 5; i++)
#pragma unroll
    for (int r = 0; r < Rr; r++) acc[i][r] = 0.f;

#pragma unroll 1
  for (int e0 = 0; e0 < En; e0 += 8) {
    float wh[8], wv[8], wsh[8], wsv[8];
#pragma unroll
    for (int j = 0; j < 8; j++) {
      int o = (e0 + j) * 256 + t;
      wh[j] = WhT[o]; wv[j] = WvT[o]; wsh[j] = WshT[o]; wsv[j] = WsvT[o];
    }
#pragma unroll
    for (int tt = 0; tt < 5; tt++) {
#pragma unroll
      for (int r = 0; r < Rr; r++) {
        int oh = __builtin_amdgcn_readfirstlane(s_offh[tt][r]) + e0;
        int ov = __builtin_amdgcn_readfirstlane(s_offv[tt][r]) + e0;
        const float* __restrict__ ph = enc + oh;
        const float* __restrict__ pv = enc + ov;
        float a = acc[tt][r];
        if (__builtin_amdgcn_readfirstlane(s_cond[tt][r])) {
#pragma unroll
          for (int j = 0; j < 8; j++) a += wh[j] * ph[j] + wv[j] * pv[j];
        } else {
#pragma unroll
          for (int j = 0; j < 8; j++) a += wsh[j] * ph[j] + wsv[j] * pv[j];
        }
        acc[tt][r] = a;
      }
    }
  }

  // ---- stage 2: m_t = edge_t @ We^T, st = max --------------------------
  float st[Rr];
#pragma unroll
  for (int r = 0; r < Rr; r++) st[r] = 0.f;

#pragma unroll 1
  for (int tt = 0; tt < 5; tt++) {
    __syncthreads();
#pragma unroll
    for (int rq = 0; rq < 4; rq++) {
      float4 v = make_float4(acc[tt][rq * 4], acc[tt][rq * 4 + 1],
                             acc[tt][rq * 4 + 2], acc[tt][rq * 4 + 3]);
      *(float4*)&xbuf[t * 20 + rq * 4] = v;
    }
    __syncthreads();
    float m[Rr];
#pragma unroll
    for (int r = 0; r < Rr; r++) m[r] = 0.f;
#pragma unroll 1
    for (int e0 = 0; e0 < En; e0 += 8) {
      float w8[8];
#pragma unroll
      for (int j = 0; j < 8; j++) w8[j] = WeT[(e0 + j) * 256 + t];
#pragma unroll
      for (int j = 0; j < 8; j++) {
        const float* xb = &xbuf[(e0 + j) * 20];
        float4 x0 = *(const float4*)(xb);
        float4 x1 = *(const float4*)(xb + 4);
        float4 x2 = *(const float4*)(xb + 8);
        float4 x3 = *(const float4*)(xb + 12);
        m[0]  += w8[j] * x0.x; m[1]  += w8[j] * x0.y;
        m[2]  += w8[j] * x0.z; m[3]  += w8[j] * x0.w;
        m[4]  += w8[j] * x1.x; m[5]  += w8[j] * x1.y;
        m[6]  += w8[j] * x1.z; m[7]  += w8[j] * x1.w;
        m[8]  += w8[j] * x2.x; m[9]  += w8[j] * x2.y;
        m[10] += w8[j] * x2.z; m[11] += w8[j] * x2.w;
        m[12] += w8[j] * x3.x; m[13] += w8[j] * x3.y;
        m[14] += w8[j] * x3.z; m[15] += w8[j] * x3.w;
      }
    }
#pragma unroll
    for (int r = 0; r < Rr; r++) st[r] = fmaxf(st[r], m[r]);
  }

  // ---- qt = relu(edge_4 + st); xbuf currently holds edge_4 -------------
  float qtv[Rr];
#pragma unroll
  for (int r = 0; r < Rr; r++) qtv[r] = fmaxf(xbuf[t * 20 + r] + st[r], 0.f);
  __syncthreads();   // everyone done reading edge_4 broadcasts
#pragma unroll
  for (int rq = 0; rq < 4; rq++) {
    float4 v = make_float4(qtv[rq * 4], qtv[rq * 4 + 1],
                           qtv[rq * 4 + 2], qtv[rq * 4 + 3]);
    *(float4*)&xbuf[t * 20 + rq * 4] = v;
  }
  __syncthreads();

  // ---- inp = qt @ Win^T + b_in ----------------------------------------
  float inp[Rr];
#pragma unroll
  for (int r = 0; r < Rr; r++) inp[r] = 0.f;
#pragma unroll 1
  for (int e0 = 0; e0 < En; e0 += 8) {
    float w8[8];
#pragma unroll
    for (int j = 0; j < 8; j++) w8[j] = WinT[(e0 + j) * 256 + t];
#pragma unroll
    for (int j = 0; j < 8; j++) {
      const float* xb = &xbuf[(e0 + j) * 20];
      float4 x0 = *(const float4*)(xb);
      float4 x1 = *(const float4*)(xb + 4);
      float4 x2 = *(const float4*)(xb + 8);
      float4 x3 = *(const float4*)(xb + 12);
      inp[0]  += w8[j] * x0.x; inp[1]  += w8[j] * x0.y;
      inp[2]  += w8[j] * x0.z; inp[3]  += w8[j] * x0.w;
      inp[4]  += w8[j] * x1.x; inp[5]  += w8[j] * x1.y;
      inp[6]  += w8[j] * x1.z; inp[7]  += w8[j] * x1.w;
      inp[8]  += w8[j] * x2.x; inp[9]  += w8[j] * x2.y;
      inp[10] += w8[j] * x2.z; inp[11] += w8[j] * x2.w;
      inp[12] += w8[j] * x3.x; inp[13] += w8[j] * x3.y;
      inp[14] += w8[j] * x3.z; inp[15] += w8[j] * x3.w;
    }
  }
  {
    float bi = b_in[t];
#pragma unroll
    for (int r = 0; r < Rr; r++) inp[r] += bi;
  }

  // ---- ctx[l][r] = enc[b,l,:] @ Wctx^T (bias folded at tanh) -----------
  float ctx[Ln][Rr];
#pragma unroll
  for (int l = 0; l < Ln; l++)
#pragma unroll
    for (int r = 0; r < Rr; r++) ctx[l][r] = 0.f;

#pragma unroll 1
  for (int e0 = 0; e0 < En; e0 += 8) {
    float w8[8];
#pragma unroll
    for (int j = 0; j < 8; j++) w8[j] = WctxT[(e0 + j) * 256 + t];
#pragma unroll
    for (int l = 0; l < Ln; l++) {
#pragma unroll
      for (int r = 0; r < Rr; r++) {
        const float* __restrict__ px = enc + ((b0 + r) * Ln + l) * En + e0;
        float c = ctx[l][r];
#pragma unroll
        for (int j = 0; j < 8; j++) c += w8[j] * px[j];
        ctx[l][r] = c;
      }
    }
  }

  // ---- att[b,l] = sum_h V[h]*tanh(inp + b_ctx + ctx); mask; 10*tanh ----
  const float Vt = V[t];
  const float bc = b_ctx[t];
  const int lane = t & 63, wid = t >> 6;

#pragma unroll 1
  for (int l = 0; l < Ln; l++) {
    float v[Rr];
#pragma unroll
    for (int r = 0; r < Rr; r++) v[r] = Vt * tanhf(inp[r] + bc + ctx[l][r]);
#pragma unroll
    for (int off = 32; off > 0; off >>= 1) {
#pragma unroll
      for (int r = 0; r < Rr; r++) v[r] += __shfl_down(v[r], off, 64);
    }
    if (lane == 0) {
#pragma unroll
      for (int r = 0; r < Rr; r++) red[wid][r] = v[r];
    }
    __syncthreads();
    if (t < Rr) {
      float a = red[0][t] + red[1][t] + red[2][t] + red[3][t];
      int b = b0 + t;
      if (!maskp[b * Ln + l]) a = NEGF;
      a = 10.f * tanhf(a);
      att_out[b * Ln + l] = a;
    }
    __syncthreads();
  }
}

// ---------------------------------------------------------------------------
// Column sums for softmax over axis 0 (fp64 accumulation).
// ---------------------------------------------------------------------------
__global__ __launch_bounds__(256) void k_colsum(const float* __restrict__ att,
                                                float* __restrict__ sbuf) {
  int l = blockIdx.x;     // 0..6
  int t = threadIdx.x;
  double s = 0.0;
  for (int b = t; b < Bn; b += 256) s += exp((double)att[b * Ln + l]);
  __shared__ double sd[256];
  sd[t] = s;
  __syncthreads();
  for (int k = 128; k > 0; k >>= 1) {
    if (t < k) sd[t] += sd[t + k];
    __syncthreads();
  }
  if (t == 0) {
    sbuf[l] = (float)sd[0];
    sbuf[7 + l] = (float)log(sd[0]);
  }
}

// ---------------------------------------------------------------------------
// Gumbel-argmax sampling (threefry, partitionable bit-stream) + outputs.
// out = [idx(B) | p(B) | new_mask(B*7)] as float32.
// ---------------------------------------------------------------------------
__global__ __launch_bounds__(256) void k_sample(const float* __restrict__ att,
                                                const float* __restrict__ sbuf,
                                                const int* __restrict__ maskp,
                                                float* __restrict__ out) {
  int b = blockIdx.x * 256 + threadIdx.x;
  if (b >= Bn) return;
  float best = -3.0e38f;
  int bi = 0;
#pragma unroll
  for (int l = 0; l < Ln; l++) {
    uint32_t n = (uint32_t)(b * Ln + l);
    uint32_t o0, o1;
    threefry2x32(0u, 42u, 0u, n, o0, o1);   // counts64 = n -> (hi=0, lo=n)
    uint32_t bits = o0 ^ o1;                 // partitionable 32-bit fold
    uint32_t fb = (bits >> 9) | 0x3f800000u;
    float f = __uint_as_float(fb) - 1.0f;
    float u = fmaxf(f, 1.1754943508222875e-38f);
    float g = -logf(-logf(u));
    float y = att[b * Ln + l] - sbuf[7 + l] + g;
    if (y > best) { best = y; bi = l; }
  }
  out[b] = (float)bi;
  out[Bn + b] = expf(att[b * Ln + bi] - sbuf[7 + bi]);
#pragma unroll
  for (int l = 0; l < Ln; l++)
    out[2 * Bn + b * Ln + l] = (float)(maskp[b * Ln + l] - ((l == bi) ? 1 : 0));
}

// ---------------------------------------------------------------------------
extern "C" void kernel_launch(void* const* d_in, const int* in_sizes, int n_in,
                              void* d_out, int out_size, void* d_ws,
                              size_t ws_size, hipStream_t stream) {
  const float* enc   = (const float*)d_in[0];
  const int*   xes   = (const int*)d_in[1];
  const int*   maskp = (const int*)d_in[2];
  const float* W_h   = (const float*)d_in[3];
  const float* W_v   = (const float*)d_in[4];
  const float* Ws_h  = (const float*)d_in[5];
  const float* Ws_v  = (const float*)d_in[6];
  const float* W_e   = (const float*)d_in[7];
  const float* W_in  = (const float*)d_in[8];
  const float* b_in  = (const float*)d_in[9];
  const float* W_ctx = (const float*)d_in[10];
  const float* b_ctx = (const float*)d_in[11];
  const float* V     = (const float*)d_in[12];

  float* ws   = (float*)d_ws;
  float* wt   = ws;                   // 7*65536 floats
  float* att  = ws + 7 * 65536;       // B*7 floats
  float* sbuf = att + Bn * Ln;        // 14 floats

  dim3 gT(256, 7);
  k_transpose<<<gT, 256, 0, stream>>>(W_h, W_v, Ws_h, Ws_v, W_e, W_in, W_ctx, wt);
  k_main<<<Bn / Rr, 256, 0, stream>>>(enc, xes, maskp, wt, b_in, b_ctx, V, att);
  k_colsum<<<7, 256, 0, stream>>>(att, sbuf);
  k_sample<<<Bn / 256, 256, 0, stream>>>(att, sbuf, maskp, (float*)d_out);
}